// Round 1
// 422.993 us; speedup vs baseline: 1.0379x; 1.0379x over previous
//
#include <hip/hip_runtime.h>
#include <hip/hip_bf16.h>
#include <math.h>

#define K_ 4
#define B_ 64
#define S_ 50
#define D_ 256
#define V_ 40000
#define H_ 4
#define DH_ 64
#define NEG_ (-1e9f)
#define SCALE_ 0.125f

typedef __attribute__((ext_vector_type(8))) __bf16 bf16x8v;
typedef __attribute__((ext_vector_type(4))) float f32x4v;

// ---------- helpers ----------
__device__ __forceinline__ float wred_sum(float v) {
#pragma unroll
  for (int off = 32; off > 0; off >>= 1) v += __shfl_xor(v, off, 64);
  return v;
}
__device__ __forceinline__ float wred_max(float v) {
#pragma unroll
  for (int off = 32; off > 0; off >>= 1) v = fmaxf(v, __shfl_xor(v, off, 64));
  return v;
}
__device__ __forceinline__ float softplusf(float x) {
  return (x > 20.f) ? x : log1pf(expf(x));
}
__device__ __forceinline__ float geluf(float x) {
  const float c = 0.7978845608028654f;  // sqrt(2/pi)
  float x3 = x * x * x;
  return 0.5f * x * (1.f + tanhf(c * (x + 0.044715f * x3)));
}
__device__ __forceinline__ float bf2f(unsigned int u) {
  return __uint_as_float(u << 16);
}
__device__ __forceinline__ unsigned short f2bf(float f) {
  unsigned u = __float_as_uint(f);
  return (unsigned short)((u + 0x7fffu + ((u >> 16) & 1u)) >> 16);
}
__device__ __forceinline__ void unp8(uint4 a, float* d) {
  d[0] = bf2f(a.x & 0xffffu); d[1] = bf2f(a.x >> 16);
  d[2] = bf2f(a.y & 0xffffu); d[3] = bf2f(a.y >> 16);
  d[4] = bf2f(a.z & 0xffffu); d[5] = bf2f(a.z >> 16);
  d[6] = bf2f(a.w & 0xffffu); d[7] = bf2f(a.w >> 16);
}
__device__ __forceinline__ bf16x8v cvt8(float4 a, float4 b) {
  bf16x8v r;
  r[0] = (__bf16)a.x; r[1] = (__bf16)a.y; r[2] = (__bf16)a.z; r[3] = (__bf16)a.w;
  r[4] = (__bf16)b.x; r[5] = (__bf16)b.y; r[6] = (__bf16)b.z; r[7] = (__bf16)b.w;
  return r;
}

// ---------- fused front: local_agg [0,256) | weight transpose-cast [256,1024)
// | gating [1024,1824).  All three are mutually independent.
__global__ __launch_bounds__(256) void front_kernel(
    const int* __restrict__ items, const int* __restrict__ adj,
    const float* __restrict__ emb, const float* __restrict__ agg_a,
    float* __restrict__ h_raw,
    const int* __restrict__ ids, const float* __restrict__ Wg,
    const float* __restrict__ Wn, const float* __restrict__ eps,
    float* __restrict__ gates,
    const float* __restrict__ wq, const float* __restrict__ wk,
    const float* __restrict__ wv, const float* __restrict__ wo,
    const float* __restrict__ w1, const float* __restrict__ w2,
    unsigned short* __restrict__ wqkvT, unsigned short* __restrict__ woT,
    unsigned short* __restrict__ w1T, unsigned short* __restrict__ w2T) {
  __shared__ __bf16 hgb[64][264];
  __shared__ float e_f[50][68];
  __shared__ __bf16 alp[64][72];
  __shared__ unsigned char adj_s[64][64];
  __shared__ __bf16 a_sb[4][264];
  int bid = blockIdx.x;
  int t = threadIdx.x;

  if (bid < 256) {
    // ======== local aggregator (MFMA) ========
    int kb = bid;
    int k = kb >> 6, b = kb & 63;
    for (int c = t; c < 2048; c += 256) {
      int row = c >> 5, c8 = (c & 31) * 8;
      bf16x8v val;
      if (row < S_) {
        int g = items[kb * S_ + row];
        const float* src = emb + ((long)k * V_ + g) * D_ + c8;
        val = cvt8(*(const float4*)src, *(const float4*)(src + 4));
      } else {
#pragma unroll
        for (int e = 0; e < 8; ++e) val[e] = (__bf16)0.f;
      }
      *(bf16x8v*)&hgb[row][c8] = val;
    }
    if (t < 128) {
      int row = t >> 5, c8 = (t & 31) * 8;
      const float* src = agg_a + ((long)k * 4 + row) * D_ + c8;
      *(bf16x8v*)&a_sb[row][c8] = cvt8(*(const float4*)src, *(const float4*)(src + 4));
    }
    for (int c = t; c < 4096; c += 256) {
      int i = c >> 6, j = c & 63;
      adj_s[i][j] = (i < S_ && j < S_)
                        ? (unsigned char)adj[((long)b * S_ + i) * S_ + j] : 0;
    }
    __syncthreads();
    int w = t >> 6, lane = t & 63;
    int m16 = lane & 15, quad = lane >> 4;
    float e_sel[4][4];
#pragma unroll
    for (int nt = 0; nt < 4; ++nt)
#pragma unroll
      for (int rg = 0; rg < 4; ++rg) e_sel[nt][rg] = NEG_;
#pragma unroll
    for (int r = 0; r < 4; ++r) {
      f32x4v acc[4];
#pragma unroll
      for (int nt = 0; nt < 4; ++nt) acc[nt] = (f32x4v){0.f, 0.f, 0.f, 0.f};
#pragma unroll
      for (int k0 = 0; k0 < 8; ++k0) {
        int kc = k0 * 32 + quad * 8;
        bf16x8v hr = *(const bf16x8v*)&hgb[w * 16 + m16][kc];
        bf16x8v ar = *(const bf16x8v*)&a_sb[r][kc];
        bf16x8v af;
#pragma unroll
        for (int e = 0; e < 8; ++e) af[e] = (__bf16)((float)hr[e] * (float)ar[e]);
#pragma unroll
        for (int nt = 0; nt < 4; ++nt) {
          bf16x8v bf = *(const bf16x8v*)&hgb[nt * 16 + m16][kc];
          acc[nt] = __builtin_amdgcn_mfma_f32_16x16x32_bf16(af, bf, acc[nt], 0, 0, 0);
        }
      }
#pragma unroll
      for (int nt = 0; nt < 4; ++nt)
#pragma unroll
        for (int rg = 0; rg < 4; ++rg) {
          int i = w * 16 + quad * 4 + rg, j = nt * 16 + m16;
          if (adj_s[i][j] == r + 1) {
            float v = acc[nt][rg];
            e_sel[nt][rg] = (v >= 0.f) ? v : 0.2f * v;
          }
        }
    }
#pragma unroll
    for (int nt = 0; nt < 4; ++nt)
#pragma unroll
      for (int rg = 0; rg < 4; ++rg) {
        int i = w * 16 + quad * 4 + rg;
        if (i < S_) e_f[i][nt * 16 + m16] = e_sel[nt][rg];
      }
    __syncthreads();
    for (int i = w; i < S_; i += 4) {
      float val = (lane < S_) ? e_f[i][lane] : -INFINITY;
      float m = wred_max(val);
      float p = expf(val - m);
      float ssum = wred_sum(p);
      alp[i][lane] = (__bf16)(p / ssum);
    }
    __syncthreads();
#pragma unroll 4
    for (int nt = 0; nt < 16; ++nt) {
      f32x4v acc = (f32x4v){0.f, 0.f, 0.f, 0.f};
#pragma unroll
      for (int k0 = 0; k0 < 2; ++k0) {
        int jb = k0 * 32 + quad * 8;
        bf16x8v af = *(const bf16x8v*)&alp[w * 16 + m16][jb];
        bf16x8v bf;
#pragma unroll
        for (int tt = 0; tt < 8; ++tt) bf[tt] = hgb[jb + tt][nt * 16 + m16];
        acc = __builtin_amdgcn_mfma_f32_16x16x32_bf16(af, bf, acc, 0, 0, 0);
      }
#pragma unroll
      for (int rg = 0; rg < 4; ++rg) {
        int i = w * 16 + quad * 4 + rg;
        if (i < S_)
          h_raw[((long)kb * S_ + i) * D_ + nt * 16 + m16] = acc[rg];
      }
    }
    return;
  }

  if (bid < 1024) {
    // ======== weight cast: LDS-tiled 64x64 transpose, coalesced both sides ====
    int tid = bid - 256;
    typedef unsigned short row66[66];
    row66* tile = (row66*)&hgb[0][0];  // reuse agg LDS (needs 8.3 KB of 33 KB)
    const float* src; unsigned short* dst; int C, R; int r0, c0;
    if (tid < 192) {  // Wq|Wk|Wv [256][256] per k -> wqkvT rows sect*256+
      int sect = tid >> 6; int rem = tid & 63;
      int k = rem >> 4, t2 = rem & 15;
      r0 = (t2 >> 2) * 64; c0 = (t2 & 3) * 64;
      src = ((sect == 0) ? wq : (sect == 1) ? wk : wv) + (long)k * 65536;
      dst = wqkvT + ((long)k * 768 + sect * 256) * 256;
      R = 256; C = 256;
    } else if (tid < 256) {  // Wo
      int rem = tid - 192; int k = rem >> 4, t2 = rem & 15;
      r0 = (t2 >> 2) * 64; c0 = (t2 & 3) * 64;
      src = wo + (long)k * 65536; dst = woT + (long)k * 65536;
      R = 256; C = 256;
    } else if (tid < 512) {  // W1 [256][1024] -> w1T [1024][256]
      int rem = tid - 256; int k = rem >> 6, t2 = rem & 63;
      r0 = (t2 >> 4) * 64; c0 = (t2 & 15) * 64;
      src = w1 + (long)k * 262144; dst = w1T + (long)k * 262144;
      R = 256; C = 1024;
    } else {  // W2 [1024][256] -> w2T [256][1024]
      int rem = tid - 512; int k = rem >> 6, t2 = rem & 63;
      r0 = (t2 >> 2) * 64; c0 = (t2 & 3) * 64;
      src = w2 + (long)k * 262144; dst = w2T + (long)k * 262144;
      R = 1024; C = 256;
    }
    int sr = t >> 2, sc = (t & 3) * 16;
    const float* p = src + (long)(r0 + sr) * C + c0 + sc;
#pragma unroll
    for (int q = 0; q < 4; ++q) {
      float4 f = *(const float4*)(p + q * 4);
      tile[sr][sc + q * 4 + 0] = f2bf(f.x);
      tile[sr][sc + q * 4 + 1] = f2bf(f.y);
      tile[sr][sc + q * 4 + 2] = f2bf(f.z);
      tile[sr][sc + q * 4 + 3] = f2bf(f.w);
    }
    __syncthreads();
    int dc = t >> 2, ch = (t & 3) * 16;  // dst row c0+dc, cols r0+ch..+16
    unsigned int wds[8];
#pragma unroll
    for (int i = 0; i < 8; ++i)
      wds[i] = (unsigned int)tile[ch + 2 * i][dc] |
               ((unsigned int)tile[ch + 2 * i + 1][dc] << 16);
    unsigned short* dp = dst + (long)(c0 + dc) * R + r0 + ch;
    uint4 o0 = make_uint4(wds[0], wds[1], wds[2], wds[3]);
    uint4 o1 = make_uint4(wds[4], wds[5], wds[6], wds[7]);
    *(uint4*)dp = o0;
    *(uint4*)(dp + 8) = o1;
    return;
  }

  {
    // ======== noisy top-k gating ========
    int w = t >> 6, lane = t & 63;
    int item = (bid - 1024) * 4 + w;  // b*S+s
    int b = item / S_, s = item % S_;
    int d0 = lane * 4;
    float4 hs = make_float4(0.f, 0.f, 0.f, 0.f);
#pragma unroll
    for (int k = 0; k < K_; ++k) {
      int id = ids[(k * B_ + b) * S_ + s];
      const float4 e = *(const float4*)(emb + ((long)k * V_ + id) * D_ + d0);
      hs.x += e.x; hs.y += e.y; hs.z += e.z; hs.w += e.w;
    }
    hs.x *= 0.25f; hs.y *= 0.25f; hs.z *= 0.25f; hs.w *= 0.25f;
    float logit[4];
#pragma unroll
    for (int j = 0; j < K_; ++j) {
      float pg = hs.x * Wg[(d0 + 0) * K_ + j] + hs.y * Wg[(d0 + 1) * K_ + j] +
                 hs.z * Wg[(d0 + 2) * K_ + j] + hs.w * Wg[(d0 + 3) * K_ + j];
      float pn = hs.x * Wn[(d0 + 0) * K_ + j] + hs.y * Wn[(d0 + 1) * K_ + j] +
                 hs.z * Wn[(d0 + 2) * K_ + j] + hs.w * Wn[(d0 + 3) * K_ + j];
      pg = wred_sum(pg);
      pn = wred_sum(pn);
      logit[j] = pg + softplusf(pn) * eps[item * K_ + j];
    }
    if (lane == 0) {
      int i0 = 0; float v0 = logit[0];
      for (int j = 1; j < K_; ++j) if (logit[j] > v0) { v0 = logit[j]; i0 = j; }
      int i1 = -1; float v1 = 0.f;
      for (int j = 0; j < K_; ++j)
        if (j != i0 && (i1 < 0 || logit[j] > v1)) { v1 = logit[j]; i1 = j; }
      float w0 = 1.f / (1.f + expf(v1 - v0));
      float w1 = 1.f - w0;
#pragma unroll
      for (int j = 0; j < K_; ++j)
        gates[item * K_ + j] = (j == i0) ? w0 : ((j == i1) ? w1 : 0.f);
    }
  }
}

// ---------- alias gather + LN1 ----------
__global__ __launch_bounds__(256) void gather_ln(
    const float* __restrict__ h_raw, const int* __restrict__ alias_,
    float* __restrict__ hbuf, unsigned short* __restrict__ xb,
    const float* __restrict__ g, const float* __restrict__ bta) {
  int kb = blockIdx.x;
  int k = kb >> 6, b = kb & 63;
  int w = threadIdx.x >> 6, lane = threadIdx.x & 63;
  for (int s = w; s < S_; s += 4) {
    int src = alias_[b * S_ + s];
    const float4 v = *(const float4*)(h_raw + ((long)kb * S_ + src) * D_ + lane * 4);
    long off = ((long)kb * S_ + s) * D_ + lane * 4;
    *(float4*)(hbuf + off) = v;
    float sum = wred_sum(v.x + v.y + v.z + v.w);
    float sq = wred_sum(v.x * v.x + v.y * v.y + v.z * v.z + v.w * v.w);
    float mean = sum * (1.f / D_);
    float var = sq * (1.f / D_) - mean * mean;
    float rs = rsqrtf(var + 1e-5f);
    const float4 gv = *(const float4*)(g + k * D_ + lane * 4);
    const float4 bv = *(const float4*)(bta + k * D_ + lane * 4);
    ushort4 o;
    o.x = f2bf((v.x - mean) * rs * gv.x + bv.x);
    o.y = f2bf((v.y - mean) * rs * gv.y + bv.y);
    o.z = f2bf((v.z - mean) * rs * gv.z + bv.z);
    o.w = f2bf((v.w - mean) * rs * gv.w + bv.w);
    *(ushort4*)(xb + off) = o;
  }
}

// ---------- bf16 MFMA GEMM v2: 64x64 tile, BK=64, Bt=[N][Kd], prefetch ----------
__global__ __launch_bounds__(256) void bgemm2(
    const unsigned short* __restrict__ A, const unsigned short* __restrict__ Bt,
    long strideA, long strideBt, int N, int Kd,
    float* __restrict__ Cf, long strideCf,
    const float* __restrict__ R, long strideR,
    unsigned short* __restrict__ Cb, long strideCb, int act) {
  __shared__ unsigned short sA[64][72];
  __shared__ unsigned short sB[64][72];
  int z = blockIdx.z;
  A += (long)z * strideA;
  Bt += (long)z * strideBt;
  int t = threadIdx.x, w = t >> 6, lane = t & 63;
  int row0 = blockIdx.x * 64, col0 = blockIdx.y * 64;
  int m16 = lane & 15, quad = lane >> 4;
  f32x4v acc[4];
#pragma unroll
  for (int nt = 0; nt < 4; ++nt) acc[nt] = (f32x4v){0.f, 0.f, 0.f, 0.f};
  int sr = t >> 2, sc = (t & 3) * 16;
  const unsigned short* pa = A + (long)(row0 + sr) * Kd + sc;
  const unsigned short* pb = Bt + (long)(col0 + sr) * Kd + sc;
  uint4 a0 = *(const uint4*)(pa);
  uint4 a1 = *(const uint4*)(pa + 8);
  uint4 b0 = *(const uint4*)(pb);
  uint4 b1 = *(const uint4*)(pb + 8);
  for (int k0 = 0; k0 < Kd; k0 += 64) {
    __syncthreads();
    *(uint4*)&sA[sr][sc] = a0;
    *(uint4*)&sA[sr][sc + 8] = a1;
    *(uint4*)&sB[sr][sc] = b0;
    *(uint4*)&sB[sr][sc + 8] = b1;
    if (k0 + 64 < Kd) {
      a0 = *(const uint4*)(pa + k0 + 64);
      a1 = *(const uint4*)(pa + k0 + 72);
      b0 = *(const uint4*)(pb + k0 + 64);
      b1 = *(const uint4*)(pb + k0 + 72);
    }
    __syncthreads();
#pragma unroll
    for (int half = 0; half < 2; ++half) {
      int kg = half * 32 + quad * 8;
      bf16x8v af = *(const bf16x8v*)&sA[w * 16 + m16][kg];
#pragma unroll
      for (int nt = 0; nt < 4; ++nt) {
        bf16x8v bf = *(const bf16x8v*)&sB[nt * 16 + m16][kg];
        acc[nt] = __builtin_amdgcn_mfma_f32_16x16x32_bf16(af, bf, acc[nt], 0, 0, 0);
      }
    }
  }
  int rbase = row0 + w * 16 + quad * 4;
  int cb = m16;
#pragma unroll
  for (int nt = 0; nt < 4; ++nt) {
#pragma unroll
    for (int i2 = 0; i2 < 4; ++i2) {
      long off = (long)(rbase + i2) * N + col0 + nt * 16 + cb;
      float vv = acc[nt][i2];
      if (R) vv += R[(long)z * strideR + off];
      if (act == 1) vv = geluf(vv);
      if (Cf) Cf[(long)z * strideCf + off] = vv;
      if (Cb) Cb[(long)z * strideCb + off] = f2bf(vv);
    }
  }
}

// ---------- causal MHA ----------
__global__ __launch_bounds__(256) void attn_kernel(
    const unsigned short* __restrict__ qkv, unsigned short* __restrict__ o) {
  __shared__ float qs[S_][65], ks[S_][65], vs[S_][65];
  int idx = blockIdx.x;
  int h = idx & 3;
  int kb = idx >> 2;
  long base = (long)kb * S_ * 768;
  int t = threadIdx.x;
  for (int f = t; f < S_ * 8; f += 256) {
    int row = f >> 3, c8 = (f & 7) * 8;
    long g = base + (long)row * 768 + h * DH_ + c8;
    unp8(*(const uint4*)(qkv + g), &qs[row][c8]);
    unp8(*(const uint4*)(qkv + g + 256), &ks[row][c8]);
    unp8(*(const uint4*)(qkv + g + 512), &vs[row][c8]);
  }
  __syncthreads();
  int w = t >> 6, lane = t & 63;
  for (int i = w; i < S_; i += 4) {
    int jj = (lane < S_) ? lane : 0;
    float dot = 0.f;
#pragma unroll
    for (int d = 0; d < DH_; ++d) dot = fmaf(qs[i][d], ks[jj][d], dot);
    float val = (lane <= i) ? dot * SCALE_ : ((lane < S_) ? NEG_ : -INFINITY);
    float m = wred_max(val);
    float p = expf(val - m);
    float ssum = wred_sum(p);
    float pr = p / ssum;
    float acc = 0.f;
    for (int j = 0; j <= i; ++j)
      acc = fmaf(__shfl(pr, j, 64), vs[j][lane], acc);
    o[((long)kb * S_ + i) * D_ + h * DH_ + lane] = f2bf(acc);
  }
}

// ---------- O-projection + residual + LN2 fused (64x256 tile, full rows) ------
__global__ __launch_bounds__(256) void bgemm_oln(
    const unsigned short* __restrict__ A, const unsigned short* __restrict__ Bt,
    float* __restrict__ hbuf, unsigned short* __restrict__ y,
    const float* __restrict__ g2, const float* __restrict__ b2) {
  __shared__ unsigned short sA[64][72];
  __shared__ unsigned short sB[256][72];
  const long BSD = (long)B_ * S_ * D_;
  int z = blockIdx.z;
  const unsigned short* Ap = A + (long)z * BSD;
  const unsigned short* Bp = Bt + (long)z * 65536;
  int t = threadIdx.x, w = t >> 6, lane = t & 63;
  int row0 = blockIdx.x * 64;
  int m16 = lane & 15, quad = lane >> 4;
  f32x4v acc[16];
#pragma unroll
  for (int nt = 0; nt < 16; ++nt) acc[nt] = (f32x4v){0.f, 0.f, 0.f, 0.f};
  int sr = t >> 2, sc = (t & 3) * 16;
  const unsigned short* pa = Ap + (long)(row0 + sr) * 256 + sc;
  const unsigned short* pb = Bp + (long)sr * 256 + sc;  // + q*64 rows = +q*16384
  uint4 a0 = *(const uint4*)pa;
  uint4 a1 = *(const uint4*)(pa + 8);
  uint4 bv[8];
#pragma unroll
  for (int q = 0; q < 4; ++q) {
    bv[2 * q] = *(const uint4*)(pb + q * 16384);
    bv[2 * q + 1] = *(const uint4*)(pb + q * 16384 + 8);
  }
  for (int k0 = 0; k0 < 256; k0 += 64) {
    __syncthreads();
    *(uint4*)&sA[sr][sc] = a0;
    *(uint4*)&sA[sr][sc + 8] = a1;
#pragma unroll
    for (int q = 0; q < 4; ++q) {
      *(uint4*)&sB[q * 64 + sr][sc] = bv[2 * q];
      *(uint4*)&sB[q * 64 + sr][sc + 8] = bv[2 * q + 1];
    }
    if (k0 + 64 < 256) {
      a0 = *(const uint4*)(pa + k0 + 64);
      a1 = *(const uint4*)(pa + k0 + 72);
#pragma unroll
      for (int q = 0; q < 4; ++q) {
        bv[2 * q] = *(const uint4*)(pb + q * 16384 + k0 + 64);
        bv[2 * q + 1] = *(const uint4*)(pb + q * 16384 + k0 + 72);
      }
    }
    __syncthreads();
#pragma unroll
    for (int half = 0; half < 2; ++half) {
      int kg = half * 32 + quad * 8;
      bf16x8v af = *(const bf16x8v*)&sA[w * 16 + m16][kg];
#pragma unroll
      for (int nt = 0; nt < 16; ++nt) {
        bf16x8v bf = *(const bf16x8v*)&sB[nt * 16 + m16][kg];
        acc[nt] = __builtin_amdgcn_mfma_f32_16x16x32_bf16(af, bf, acc[nt], 0, 0, 0);
      }
    }
  }
  // epilogue: v = gemm + h  ->  hbuf (residual); LN(v) -> y bf16
  long zoff = (long)z * BSD;
  int rbase = row0 + w * 16 + quad * 4;
#pragma unroll
  for (int nt = 0; nt < 16; ++nt)
#pragma unroll
    for (int i2 = 0; i2 < 4; ++i2) {
      long off = zoff + (long)(rbase + i2) * 256 + nt * 16 + m16;
      float vv = acc[nt][i2] + hbuf[off];
      acc[nt][i2] = vv;
      hbuf[off] = vv;
    }
  float mean[4], rstd[4];
#pragma unroll
  for (int i2 = 0; i2 < 4; ++i2) {
    float s = 0.f, q = 0.f;
#pragma unroll
    for (int nt = 0; nt < 16; ++nt) {
      float vv = acc[nt][i2];
      s += vv; q += vv * vv;
    }
#pragma unroll
    for (int off = 1; off < 16; off <<= 1) {  // reduce over m16 lanes (same quad)
      s += __shfl_xor(s, off, 64);
      q += __shfl_xor(q, off, 64);
    }
    float m = s * (1.f / D_);
    float var = q * (1.f / D_) - m * m;
    mean[i2] = m;
    rstd[i2] = rsqrtf(var + 1e-5f);
  }
#pragma unroll
  for (int nt = 0; nt < 16; ++nt) {
    float gv = g2[z * D_ + nt * 16 + m16];
    float bvv = b2[z * D_ + nt * 16 + m16];
#pragma unroll
    for (int i2 = 0; i2 < 4; ++i2) {
      long off = zoff + (long)(rbase + i2) * 256 + nt * 16 + m16;
      y[off] = f2bf((acc[nt][i2] - mean[i2]) * rstd[i2] * gv + bvv);
    }
  }
}

// ---------- FFN2 + residual + gated combine fused (z-loop inside block) -------
__global__ __launch_bounds__(256) void bgemm_f2c(
    const unsigned short* __restrict__ A, const unsigned short* __restrict__ Bt,
    const float* __restrict__ hbuf, const float* __restrict__ gates,
    float* __restrict__ out) {
  __shared__ unsigned short sA[64][72];
  __shared__ unsigned short sB[64][72];
  const long T4 = 3276800;   // per-key stride of tb [3200][1024]
  const long BSD = (long)B_ * S_ * D_;
  int t = threadIdx.x, w = t >> 6, lane = t & 63;
  int row0 = blockIdx.x * 64, col0 = blockIdx.y * 64;
  int m16 = lane & 15, quad = lane >> 4;
  int rbase = row0 + w * 16 + quad * 4;
  float racc[4][4];
#pragma unroll
  for (int nt = 0; nt < 4; ++nt)
#pragma unroll
    for (int i2 = 0; i2 < 4; ++i2) racc[nt][i2] = 0.f;
  int sr = t >> 2, sc = (t & 3) * 16;
  for (int z = 0; z < K_; ++z) {
    const unsigned short* pa = A + (long)z * T4 + (long)(row0 + sr) * 1024 + sc;
    const unsigned short* pb = Bt + (long)z * 262144 + (long)(col0 + sr) * 1024 + sc;
    f32x4v acc[4];
#pragma unroll
    for (int nt = 0; nt < 4; ++nt) acc[nt] = (f32x4v){0.f, 0.f, 0.f, 0.f};
    uint4 a0 = *(const uint4*)pa;
    uint4 a1 = *(const uint4*)(pa + 8);
    uint4 b0 = *(const uint4*)pb;
    uint4 b1 = *(const uint4*)(pb + 8);
    for (int k0 = 0; k0 < 1024; k0 += 64) {
      __syncthreads();
      *(uint4*)&sA[sr][sc] = a0;
      *(uint4*)&sA[sr][sc + 8] = a1;
      *(uint4*)&sB[sr][sc] = b0;
      *(uint4*)&sB[sr][sc + 8] = b1;
      if (k0 + 64 < 1024) {
        a0 = *(const uint4*)(pa + k0 + 64);
        a1 = *(const uint4*)(pa + k0 + 72);
        b0 = *(const uint4*)(pb + k0 + 64);
        b1 = *(const uint4*)(pb + k0 + 72);
      }
      __syncthreads();
#pragma unroll
      for (int half = 0; half < 2; ++half) {
        int kg = half * 32 + quad * 8;
        bf16x8v af = *(const bf16x8v*)&sA[w * 16 + m16][kg];
#pragma unroll
        for (int nt = 0; nt < 4; ++nt) {
          bf16x8v bf = *(const bf16x8v*)&sB[nt * 16 + m16][kg];
          acc[nt] = __builtin_amdgcn_mfma_f32_16x16x32_bf16(af, bf, acc[nt], 0, 0, 0);
        }
      }
    }
    // gated accumulate: racc += g_z * (gemm + h_z)
#pragma unroll
    for (int i2 = 0; i2 < 4; ++i2) {
      float gz = gates[(rbase + i2) * 4 + z];
#pragma unroll
      for (int nt = 0; nt < 4; ++nt) {
        long off = (long)z * BSD + (long)(rbase + i2) * 256 + col0 + nt * 16 + m16;
        racc[nt][i2] += gz * (acc[nt][i2] + hbuf[off]);
      }
    }
  }
#pragma unroll
  for (int nt = 0; nt < 4; ++nt)
#pragma unroll
    for (int i2 = 0; i2 < 4; ++i2)
      out[(long)(rbase + i2) * 256 + col0 + nt * 16 + m16] = racc[nt][i2];
}

extern "C" void kernel_launch(void* const* d_in, const int* in_sizes, int n_in,
                              void* d_out, int out_size, void* d_ws,
                              size_t ws_size, hipStream_t stream) {
  const int* ids = (const int*)d_in[0];
  const int* items = (const int*)d_in[1];
  const int* adj = (const int*)d_in[2];
  const int* alias = (const int*)d_in[3];
  const float* eps = (const float*)d_in[4];
  const float* emb = (const float*)d_in[5];
  const float* agg_a = (const float*)d_in[6];
  const float* Wq = (const float*)d_in[7];
  const float* Wk = (const float*)d_in[8];
  const float* Wv = (const float*)d_in[9];
  const float* Wo = (const float*)d_in[10];
  const float* ln1g = (const float*)d_in[11];
  const float* ln1b = (const float*)d_in[12];
  const float* W1 = (const float*)d_in[13];
  const float* W2 = (const float*)d_in[14];
  const float* ln2g = (const float*)d_in[15];
  const float* ln2b = (const float*)d_in[16];
  const float* Wg = (const float*)d_in[17];
  const float* Wn = (const float*)d_in[18];
  float* out = (float*)d_out;

  const long BSD = (long)B_ * S_ * D_;  // 819200
  float* ws = (float*)d_ws;
  float* gates = ws;                    // 16384 fp32
  float* hbuf = ws + 16384;             // [K,B,S,D] fp32 residual stream
  unsigned short* ub = (unsigned short*)(ws + 16384 + 4 * BSD);
  unsigned short* xb = ub;              // x / attn-o / y slot [K,B,S,D] bf16
  unsigned short* qkvb = ub + 3276800;  // [K,B*S,768]
  unsigned short* tb = qkvb;            // FFN hidden [K,B*S,1024]
  float* h_raw = (float*)qkvb;          // pre-alias h_local (dead before QKV)
  unsigned short* wqkvT = ub + 16384000;
  unsigned short* woT = wqkvT + 786432;
  unsigned short* w1T = woT + 262144;
  unsigned short* w2T = w1T + 1048576;

  const long T4 = 3276800;

  // fused: local_agg (256) | weight transpose-cast (768) | gating (800)
  front_kernel<<<1824, 256, 0, stream>>>(
      items, adj, emb, agg_a, h_raw, ids, Wg, Wn, eps, gates,
      Wq, Wk, Wv, Wo, W1, W2, wqkvT, woT, w1T, w2T);
  gather_ln<<<256, 256, 0, stream>>>(h_raw, alias, hbuf, xb, ln1g, ln1b);
  // fused QKV projection -> qkvb
  bgemm2<<<dim3(50, 12, 4), 256, 0, stream>>>(xb, wqkvT, BSD, 196608, 768, 256,
      (float*)0, 0, (const float*)0, 0, qkvb, 2457600, 0);
  attn_kernel<<<K_ * B_ * H_, 256, 0, stream>>>(qkvb, xb);  // o -> xb
  // O projection + residual + LN2 -> hbuf fp32 (h), xb bf16 (y)
  bgemm_oln<<<dim3(50, 1, 4), 256, 0, stream>>>(xb, woT, hbuf, xb, ln2g, ln2b);
  // FFN1: gelu(y@W1) -> tb bf16
  bgemm2<<<dim3(50, 16, 4), 256, 0, stream>>>(xb, w1T, BSD, 262144, 1024, 256,
      (float*)0, 0, (const float*)0, 0, tb, T4, 1);
  // FFN2 + residual + gated combine -> out
  bgemm_f2c<<<dim3(50, 4), 256, 0, stream>>>(tb, w2T, hbuf, gates, out);
}